// Round 16
// baseline (102.969 us; speedup 1.0000x reference)
//
#include <hip/hip_runtime.h>
#include <hip/hip_bf16.h>
#include <hip/hip_fp16.h>
#include <hip/hip_fp8.h>

// Problem constants: B=1,R=2,D=256,NH=8,NP=8,ZA=4,H=W=128,Q=16384,HD=32
#define QN 16384
#define DK 256

typedef float f4_t __attribute__((ext_vector_type(4)));
typedef float f2_t __attribute__((ext_vector_type(2)));
typedef short s16x8 __attribute__((ext_vector_type(8)));
typedef short s16x4 __attribute__((ext_vector_type(4)));
typedef unsigned int u32;
typedef u32 u32x4 __attribute__((ext_vector_type(4)));
typedef u32 u32x2 __attribute__((ext_vector_type(2)));
typedef __fp16 h2_t __attribute__((ext_vector_type(2)));

__device__ inline short f2bf(float f){
  __hip_bfloat16 h = __float2bfloat16(f);
  return __builtin_bit_cast(short, h);
}
__device__ inline u32 pk2h(float a, float b){
#if __has_builtin(__builtin_amdgcn_cvt_pkrtz)
  h2_t r = __builtin_amdgcn_cvt_pkrtz(a, b);
  return __builtin_bit_cast(u32, r);
#else
  return (u32)__builtin_bit_cast(unsigned short, __float2half(a)) |
         ((u32)__builtin_bit_cast(unsigned short, __float2half(b)) << 16);
#endif
}
// fp8 e4m3 pack (2 floats -> low 16 bits) / unpack (HI = immediate template arg)
__device__ inline u32 pk_fp8(float a, float b){
#if __has_builtin(__builtin_amdgcn_cvt_pk_fp8_f32)
  return (u32)__builtin_amdgcn_cvt_pk_fp8_f32(a, b, 0, false);
#else
  __hip_fp8_e4m3 fa(a), fb(b);
  return (u32)fa.__x | ((u32)fb.__x << 8);
#endif
}
template<bool HI>
__device__ inline f2_t upk_fp8(u32 w){
#if __has_builtin(__builtin_amdgcn_cvt_pk_f32_fp8)
  return __builtin_amdgcn_cvt_pk_f32_fp8(w, HI);
#else
  const u32 hh = HI ? (w >> 16) : (w & 0xFFFFu);
  __hip_fp8_e4m3 a, b;
  a.__x = (unsigned char)(hh & 0xFF);
  b.__x = (unsigned char)(hh >> 8);
  return (f2_t){(float)a, (float)b};
#endif
}
// load 8 f32 weights and pack to bf16x8
__device__ inline s16x8 ldw8(const float* __restrict__ src){
  const f4_t v0 = *(const f4_t*)src;
  const f4_t v1 = *(const f4_t*)(src + 4);
  s16x8 o = { f2bf(v0[0]), f2bf(v0[1]), f2bf(v0[2]), f2bf(v0[3]),
              f2bf(v1[0]), f2bf(v1[1]), f2bf(v1[2]), f2bf(v1[3]) };
  return o;
}

// =============== K1: fused projection GEMM ======================================
// bid < 512:  value-proj tile (BM=64) -> fp8 gather layout vfp8 (LDS-transposed)
// bid >= 512: offset/logit tile (BM=32) -> offw/logit f32
__global__ __launch_bounds__(256, 2) void k_proj(const float* __restrict__ value,
    const float* __restrict__ query, const float* __restrict__ Wval,
    const float* __restrict__ Woff, const float* __restrict__ Wattn,
    const float* __restrict__ bval, const float* __restrict__ boff,
    const float* __restrict__ battn, char* __restrict__ vfp8,
    float* __restrict__ offw, float* __restrict__ logit){
  __shared__ short As[64 * 256];
  __shared__ short Bs[64 * 256];
  __shared__ u32 Cs[64 * 16];                 // 4KB fp8 transpose buffer (val path)
  const int tid = threadIdx.x;
  const int lane = tid & 63, wv = tid >> 6;
  const int r16 = lane & 15, kh = lane >> 4;
  const int swsel = (r16 & 7) << 4;
  const int bid = blockIdx.x;

  if (bid < 512){
    // ---------------- value-projection path (BM=64) ----------------
    const float* A = value;
    const int mbase = bid * 64;
    #pragma unroll
    for (int i = 0; i < 16; ++i){
      const int lin = i * 256 + tid;
      const int r = lin >> 6, ck = lin & 63;
      const f4_t v = *(const f4_t*)(A + (size_t)(mbase + r) * DK + ck * 4);
      s16x4 o = { f2bf(v[0]), f2bf(v[1]), f2bf(v[2]), f2bf(v[3]) };
      *(s16x4*)((char*)As + r * 512 + ((ck * 8) ^ ((r & 7) << 4))) = o;
    }
    s16x8 breg[8];
    #pragma unroll
    for (int i = 0; i < 8; ++i){
      const int lin = i * 256 + tid;
      const int n = lin >> 5, ck = lin & 31;
      breg[i] = ldw8(Wval + (size_t)n * DK + ck * 8);
    }
    __syncthreads();
    for (int cg = 0; cg < 4; ++cg){
      #pragma unroll
      for (int i = 0; i < 8; ++i){
        const int lin = i * 256 + tid;
        const int n = lin >> 5, ck = lin & 31;
        *(s16x8*)((char*)Bs + n * 512 + ((ck * 16) ^ ((n & 7) << 4))) = breg[i];
      }
      __syncthreads();
      if (cg < 3){
        #pragma unroll
        for (int i = 0; i < 8; ++i){
          const int lin = i * 256 + tid;
          const int n = lin >> 5, ck = lin & 31;
          breg[i] = ldw8(Wval + (size_t)((cg + 1) * 64 + n) * DK + ck * 8);
        }
      }
      f4_t acc[4];
      #pragma unroll
      for (int i = 0; i < 4; ++i) acc[i] = (f4_t){0.f, 0.f, 0.f, 0.f};
      #pragma unroll
      for (int kk = 0; kk < 8; ++kk){
        const int kb = kh * 16 + kk * 64;
        const s16x8 a = *(const s16x8*)((char*)As + (wv * 16 + r16) * 512 + (kb ^ swsel));
        #pragma unroll
        for (int nt = 0; nt < 4; ++nt){
          const s16x8 b = *(const s16x8*)((char*)Bs + (nt * 16 + r16) * 512 + (kb ^ swsel));
          acc[nt] = __builtin_amdgcn_mfma_f32_16x16x32_bf16(a, b, acc[nt], 0, 0, 0);
        }
      }
      // epilogue: f32 -> fp8, LDS transpose, coalesced 16B stores
      #pragma unroll
      for (int nt = 0; nt < 4; ++nt){
        const int n = cg * 64 + nt * 16 + r16;
        const float bv = bval[n];
        #pragma unroll
        for (int rix = 0; rix < 4; ++rix){
          const float vv = acc[nt][rix] + bv;
          ((char*)Cs)[(wv * 16 + kh * 4 + rix) * 64 + nt * 16 + r16] =
              (char)(pk_fp8(vv, 0.f) & 0xFFu);
        }
      }
      __syncthreads();                          // Cs ready; also fences Bs reads
      {
        const u32x4 cw = *((const u32x4*)((const char*)Cs + tid * 16));
        const int pixl = tid >> 2, q4 = tid & 3;
        const int h2 = cg * 2 + (q4 >> 1);
        const int m = mbase + pixl;
        const int r = m >> 14, pix = m & (QN - 1);
        *(u32x4*)(vfp8 + ((size_t)((r * 8 + h2) * QN + pix)) * 32 + (q4 & 1) * 16) = cw;
      }
    }
  } else {
    // ---------------- offset/logit path (BM=32) ----------------
    const float* A = query;
    const int mg = wv & 1, ch = wv >> 1;
    const int mbase = (bid - 512) * 32;
    #pragma unroll
    for (int i = 0; i < 8; ++i){
      const int lin = i * 256 + tid;
      const int r = lin >> 6, ck = lin & 63;
      const f4_t v = *(const f4_t*)(A + (size_t)(mbase + r) * DK + ck * 4);
      s16x4 o = { f2bf(v[0]), f2bf(v[1]), f2bf(v[2]), f2bf(v[3]) };
      *(s16x4*)((char*)As + r * 512 + ((ck * 8) ^ ((r & 7) << 4))) = o;
    }
    s16x8 breg[8];
    #pragma unroll
    for (int i = 0; i < 8; ++i){
      const int lin = i * 256 + tid;
      const int n = lin >> 5, ck = lin & 31;
      breg[i] = ldw8(Woff + (size_t)n * DK + ck * 8);
    }
    __syncthreads();
    for (int cg = 0; cg < 3; ++cg){
      #pragma unroll
      for (int i = 0; i < 8; ++i){
        const int lin = i * 256 + tid;
        const int n = lin >> 5, ck = lin & 31;
        *(s16x8*)((char*)Bs + n * 512 + ((ck * 16) ^ ((n & 7) << 4))) = breg[i];
      }
      __syncthreads();
      if (cg < 2){
        #pragma unroll
        for (int i = 0; i < 8; ++i){
          const int lin = i * 256 + tid;
          const int n = lin >> 5, ck = lin & 31;
          const int rrow = (cg + 1) * 64 + n;     // [64,192)
          const float* src = (rrow < 128) ? (Woff  + (size_t)rrow * DK)
                                          : (Wattn + (size_t)(rrow - 128) * DK);
          breg[i] = ldw8(src + ck * 8);
        }
      }
      f4_t acc[2];
      acc[0] = (f4_t){0.f,0.f,0.f,0.f}; acc[1] = (f4_t){0.f,0.f,0.f,0.f};
      #pragma unroll
      for (int kk = 0; kk < 8; ++kk){
        const int kb = kh * 16 + kk * 64;
        const s16x8 a = *(const s16x8*)((char*)As + (mg * 16 + r16) * 512 + (kb ^ swsel));
        #pragma unroll
        for (int nt = 0; nt < 2; ++nt){
          const s16x8 b = *(const s16x8*)((char*)Bs + (ch * 32 + nt * 16 + r16) * 512 + (kb ^ swsel));
          acc[nt] = __builtin_amdgcn_mfma_f32_16x16x32_bf16(a, b, acc[nt], 0, 0, 0);
        }
      }
      #pragma unroll
      for (int nt = 0; nt < 2; ++nt){
        const int n = cg * 64 + ch * 32 + nt * 16 + r16;
        #pragma unroll
        for (int rix = 0; rix < 4; ++rix){
          const int m = mbase + mg * 16 + kh * 4 + rix;
          const float v = acc[nt][rix];
          if (n < 128) offw[(size_t)m * 128 + n] = v + boff[n];
          else         logit[(size_t)m * 64 + (n - 128)] = v + battn[n - 128];
        }
      }
      __syncthreads();
    }
  }
}

// =============== K4: output projection + bias + residual, BM=32 =================
__global__ __launch_bounds__(256, 2) void k_gemm_out(const short* __restrict__ Ab,
    const float* __restrict__ Wout, const float* __restrict__ bout,
    const float* __restrict__ query, float* __restrict__ out){
  __shared__ short As[32 * 256];
  __shared__ short Bs[64 * 256];
  const int tid = threadIdx.x;
  const int lane = tid & 63, wv = tid >> 6;
  const int r16 = lane & 15, kh = lane >> 4;
  const int mg = wv & 1, ch = wv >> 1;
  const int swsel = (r16 & 7) << 4;
  const int mbase = blockIdx.x * 32;

  #pragma unroll
  for (int i = 0; i < 4; ++i){
    const int lin = i * 256 + tid;
    const int r = lin >> 5, ck = lin & 31;
    const s16x8 v = *(const s16x8*)(Ab + (size_t)(mbase + r) * DK + ck * 8);
    *(s16x8*)((char*)As + r * 512 + ((ck * 16) ^ ((r & 7) << 4))) = v;
  }
  s16x8 breg[8];
  #pragma unroll
  for (int i = 0; i < 8; ++i){
    const int lin = i * 256 + tid;
    const int n = lin >> 5, ck = lin & 31;
    breg[i] = ldw8(Wout + (size_t)n * DK + ck * 8);
  }
  __syncthreads();

  for (int cg = 0; cg < 4; ++cg){
    #pragma unroll
    for (int i = 0; i < 8; ++i){
      const int lin = i * 256 + tid;
      const int n = lin >> 5, ck = lin & 31;
      *(s16x8*)((char*)Bs + n * 512 + ((ck * 16) ^ ((n & 7) << 4))) = breg[i];
    }
    __syncthreads();
    if (cg < 3){
      #pragma unroll
      for (int i = 0; i < 8; ++i){
        const int lin = i * 256 + tid;
        const int n = lin >> 5, ck = lin & 31;
        breg[i] = ldw8(Wout + (size_t)((cg + 1) * 64 + n) * DK + ck * 8);
      }
    }
    f4_t acc[2];
    acc[0] = (f4_t){0.f,0.f,0.f,0.f}; acc[1] = (f4_t){0.f,0.f,0.f,0.f};
    #pragma unroll
    for (int kk = 0; kk < 8; ++kk){
      const int kb = kh * 16 + kk * 64;
      const s16x8 a = *(const s16x8*)((char*)As + (mg * 16 + r16) * 512 + (kb ^ swsel));
      #pragma unroll
      for (int nt = 0; nt < 2; ++nt){
        const s16x8 b = *(const s16x8*)((char*)Bs + (ch * 32 + nt * 16 + r16) * 512 + (kb ^ swsel));
        acc[nt] = __builtin_amdgcn_mfma_f32_16x16x32_bf16(a, b, acc[nt], 0, 0, 0);
      }
    }
    #pragma unroll
    for (int nt = 0; nt < 2; ++nt){
      const int n = cg * 64 + ch * 32 + nt * 16 + r16;
      const float bo = bout[n];
      #pragma unroll
      for (int rix = 0; rix < 4; ++rix){
        const int m = mbase + mg * 16 + kh * 4 + rix;
        out[(size_t)m * DK + n] = acc[nt][rix] + bo + query[(size_t)m * DK + n];
      }
    }
    __syncthreads();
  }
}

// ---------------- K3: bilinear sampling, fp8 v-cache, 16B-per-lane loads --------
__device__ inline void mkw(float rx, float ry, float ox, float oy, float awp,
                           u32& word, u32& pk01, u32& pk23){
  const float x = fmaf(rx, 128.f, ox) - 0.5f;
  const float y = fmaf(ry, 128.f, oy) - 0.5f;
  const float xf = floorf(x), yf = floorf(y);
  const float wx = x - xf, wy = y - yf;
  const int ix = (int)xf, iy = (int)yf;
  float xw0 = 1.f - wx, xw1 = wx, yw0 = 1.f - wy, yw1 = wy;
  if (ix < 0 || ix > 127)   xw0 = 0.f;
  if (ix < -1 || ix > 126)  xw1 = 0.f;
  if (iy < 0 || iy > 127)   yw0 = 0.f;
  if (iy < -1 || iy > 126)  yw1 = 0.f;
  const int ix0 = min(max(ix, 0), 127), ix1 = min(max(ix + 1, 0), 127);
  const int iy0 = min(max(iy, 0), 127), iy1 = min(max(iy + 1, 0), 127);
  const float t0 = awp * yw0, t1 = awp * yw1;
  pk01 = pk2h(t0 * xw0, t0 * xw1);     // (row0: x0-w, x1-w) fp16
  pk23 = pk2h(t1 * xw0, t1 * xw1);     // (row1: x0-w, x1-w) fp16
  word = (u32)(iy0 * 128 + ix0) | ((u32)(ix1 - ix0) << 16) | ((u32)(iy1 - iy0) << 17);
}

__global__ __launch_bounds__(256) void k_sampler(const float* __restrict__ rp,
    const float* __restrict__ offw, const float* __restrict__ logit,
    const char* __restrict__ vfp8, short* __restrict__ O2b){
  const int tid = threadIdx.x;
  const int j3 = tid & 7;               // lane in group
  const int row2 = j3 >> 2;             // row (y0 / y1)
  const int px2 = (j3 >> 1) & 1;        // pixel side (x0 / x1)
  const int ck2 = j3 & 1;               // channel half: [16*ck2, 16*ck2+16)
  const int grp = tid >> 3;             // query in block: 0..31
  const int lane = tid & 63;
  const int glane8 = lane & ~7;
  const int h = blockIdx.x & 7;
  const int q = (blockIdx.x >> 3) * 32 + grp;
  const u32 laneof = (u32)ck2 * 16;     // byte offset of my channel half

  const float* lp = logit + (size_t)q * 64 + h * 8;
  const float l = lp[j3];
  float m = l;
  m = fmaxf(m, __shfl_xor(m, 1)); m = fmaxf(m, __shfl_xor(m, 2)); m = fmaxf(m, __shfl_xor(m, 4));
  const float e = __expf(l - m);
  float ssum = e;
  ssum += __shfl_xor(ssum, 1); ssum += __shfl_xor(ssum, 2); ssum += __shfl_xor(ssum, 4);
  const float awp = e * (0.5f / ssum);

  const float* offp = offw + (size_t)q * 128 + h * 16;
  const float ox = offp[2 * j3], oy = offp[2 * j3 + 1];
  const int za2 = (j3 & 3) * 2;
  const float rx0 = rp[(size_t)q * 8 + za2],        ry0 = rp[(size_t)q * 8 + za2 + 1];
  const float rx1 = rp[(size_t)(QN + q) * 8 + za2], ry1 = rp[(size_t)(QN + q) * 8 + za2 + 1];

  u32 wrdA, pkA01, pkA23, wrdB, pkB01, pkB23;
  mkw(rx0, ry0, ox, oy, awp, wrdA, pkA01, pkA23);   // r=0 sample (owner: lane j3 = p)
  mkw(rx1, ry1, ox, oy, awp, wrdB, pkB01, pkB23);   // r=1 sample

  const char* vb0 = vfp8 + (size_t)(h * QN) * 32;
  const char* vb1 = vfp8 + (size_t)((8 + h) * QN) * 32;

  float acc[16];
  #pragma unroll
  for (int i = 0; i < 16; ++i) acc[i] = 0.f;

#define LOADP(S, WRD, VB)                                                   \
  const u32 wd_##S = __shfl((WRD), glane8 | ((S) & 7));                     \
  const u32 ad_##S = (wd_##S & 0xFFFFu) * 32u + laneof                      \
                   + (px2 ? ((wd_##S >> 11) & 32u) : 0u)                    \
                   + (row2 ? ((wd_##S >> 17) & 1u) * 4096u : 0u);           \
  const u32x4 c_##S = *(const u32x4*)((VB) + ad_##S);

#define USEP(S, PK01, PK23) do{                                             \
    const int srcl_ = glane8 | ((S) & 7);                                   \
    const u32 w01_ = __shfl((PK01), srcl_);                                 \
    const u32 w23_ = __shfl((PK23), srcl_);                                 \
    const u32 wsel_ = row2 ? w23_ : w01_;                                   \
    const h2_t wh_ = __builtin_bit_cast(h2_t, wsel_);                       \
    const float w_ = px2 ? (float)wh_[1] : (float)wh_[0];                   \
    _Pragma("unroll")                                                       \
    for (int i_ = 0; i_ < 4; ++i_){                                         \
      const f2_t lo_ = upk_fp8<false>(c_##S[i_]);                           \
      const f2_t hi_ = upk_fp8<true >(c_##S[i_]);                           \
      acc[4*i_+0] = fmaf(w_, lo_[0], acc[4*i_+0]);                          \
      acc[4*i_+1] = fmaf(w_, lo_[1], acc[4*i_+1]);                          \
      acc[4*i_+2] = fmaf(w_, hi_[0], acc[4*i_+2]);                          \
      acc[4*i_+3] = fmaf(w_, hi_[1], acc[4*i_+3]);                          \
    }                                                                       \
  }while(0)

  LOADP(0,  wrdA, vb0) LOADP(1,  wrdA, vb0) LOADP(2,  wrdA, vb0)
  USEP(0,  pkA01, pkA23); LOADP(3,  wrdA, vb0)
  USEP(1,  pkA01, pkA23); LOADP(4,  wrdA, vb0)
  USEP(2,  pkA01, pkA23); LOADP(5,  wrdA, vb0)
  USEP(3,  pkA01, pkA23); LOADP(6,  wrdA, vb0)
  USEP(4,  pkA01, pkA23); LOADP(7,  wrdA, vb0)
  USEP(5,  pkA01, pkA23); LOADP(8,  wrdB, vb1)
  USEP(6,  pkA01, pkA23); LOADP(9,  wrdB, vb1)
  USEP(7,  pkA01, pkA23); LOADP(10, wrdB, vb1)
  USEP(8,  pkB01, pkB23); LOADP(11, wrdB, vb1)
  USEP(9,  pkB01, pkB23); LOADP(12, wrdB, vb1)
  USEP(10, pkB01, pkB23); LOADP(13, wrdB, vb1)
  USEP(11, pkB01, pkB23); LOADP(14, wrdB, vb1)
  USEP(12, pkB01, pkB23); LOADP(15, wrdB, vb1)
  USEP(13, pkB01, pkB23);
  USEP(14, pkB01, pkB23);
  USEP(15, pkB01, pkB23);
#undef LOADP
#undef USEP

  #pragma unroll
  for (int i = 0; i < 16; ++i) acc[i] += __shfl_xor(acc[i], 4);
  #pragma unroll
  for (int i = 0; i < 16; ++i) acc[i] += __shfl_xor(acc[i], 2);
  if (j3 < 2){
    short* op = O2b + (size_t)q * DK + h * 32 + j3 * 16;
    s16x8 o0 = { f2bf(acc[0]),  f2bf(acc[1]),  f2bf(acc[2]),  f2bf(acc[3]),
                 f2bf(acc[4]),  f2bf(acc[5]),  f2bf(acc[6]),  f2bf(acc[7]) };
    s16x8 o1 = { f2bf(acc[8]),  f2bf(acc[9]),  f2bf(acc[10]), f2bf(acc[11]),
                 f2bf(acc[12]), f2bf(acc[13]), f2bf(acc[14]), f2bf(acc[15]) };
    *(s16x8*)op       = o0;
    *(s16x8*)(op + 8) = o1;
  }
}

extern "C" void kernel_launch(void* const* d_in, const int* in_sizes, int n_in,
                              void* d_out, int out_size, void* d_ws, size_t ws_size,
                              hipStream_t stream) {
  const float* query = (const float*)d_in[0];
  const float* value = (const float*)d_in[1];
  const float* refpt = (const float*)d_in[2];
  // d_in[3] spatial_shapes: fixed [[128,128]], hardcoded
  const float* W_off  = (const float*)d_in[4];
  const float* b_off  = (const float*)d_in[5];
  const float* W_attn = (const float*)d_in[6];
  const float* b_attn = (const float*)d_in[7];
  const float* W_val  = (const float*)d_in[8];
  const float* b_val  = (const float*)d_in[9];
  const float* W_out  = (const float*)d_in[10];
  const float* b_out  = (const float*)d_in[11];
  float* out = (float*)d_out;

  char* ws = (char*)d_ws;
  char*  vfp8 = (char*)(ws);                     // 2*8*16384*32 fp8      (8388608 B)
  float* offw = (float*)(ws + 8388608);          // 16384*128 f32         (8388608 B)
  float* logit= (float*)(ws + 16777216);         // 16384*64 f32          (4194304 B)
  short* O2b  = (short*)(ws + 20971520);         // 16384*256 bf16        (8388608 B)

  // MEASUREMENT ROUND: k_proj and k_gemm_out launched twice (both idempotent).
  // Delta vs R13's 67.6 us = proj + out duration.
  k_proj    <<<dim3(1024), dim3(256), 0, stream>>>(value, query, W_val, W_off, W_attn,
                                                   b_val, b_off, b_attn, vfp8, offw, logit);
  k_proj    <<<dim3(1024), dim3(256), 0, stream>>>(value, query, W_val, W_off, W_attn,
                                                   b_val, b_off, b_attn, vfp8, offw, logit);
  k_sampler <<<dim3(4096), dim3(256), 0, stream>>>(refpt, offw, logit, vfp8, O2b);
  k_gemm_out<<<dim3(512),  dim3(256), 0, stream>>>(O2b, W_out, b_out, query, out);
  k_gemm_out<<<dim3(512),  dim3(256), 0, stream>>>(O2b, W_out, b_out, query, out);
}

// Round 17
// 75.266 us; speedup vs baseline: 1.3681x; 1.3681x over previous
//
#include <hip/hip_runtime.h>
#include <hip/hip_bf16.h>
#include <hip/hip_fp16.h>
#include <hip/hip_fp8.h>

// Problem constants: B=1,R=2,D=256,NH=8,NP=8,ZA=4,H=W=128,Q=16384,HD=32
#define QN 16384
#define DK 256

typedef float f4_t __attribute__((ext_vector_type(4)));
typedef float f2_t __attribute__((ext_vector_type(2)));
typedef short s16x8 __attribute__((ext_vector_type(8)));
typedef short s16x4 __attribute__((ext_vector_type(4)));
typedef unsigned int u32;
typedef u32 u32x4 __attribute__((ext_vector_type(4)));
typedef u32 u32x2 __attribute__((ext_vector_type(2)));
typedef __fp16 h2_t __attribute__((ext_vector_type(2)));

__device__ inline short f2bf(float f){
  __hip_bfloat16 h = __float2bfloat16(f);
  return __builtin_bit_cast(short, h);
}
__device__ inline u32 pk2h(float a, float b){
#if __has_builtin(__builtin_amdgcn_cvt_pkrtz)
  h2_t r = __builtin_amdgcn_cvt_pkrtz(a, b);
  return __builtin_bit_cast(u32, r);
#else
  return (u32)__builtin_bit_cast(unsigned short, __float2half(a)) |
         ((u32)__builtin_bit_cast(unsigned short, __float2half(b)) << 16);
#endif
}
// fp8 e4m3 pack (2 floats -> low 16 bits) / unpack (HI = immediate template arg)
__device__ inline u32 pk_fp8(float a, float b){
#if __has_builtin(__builtin_amdgcn_cvt_pk_fp8_f32)
  return (u32)__builtin_amdgcn_cvt_pk_fp8_f32(a, b, 0, false);
#else
  __hip_fp8_e4m3 fa(a), fb(b);
  return (u32)fa.__x | ((u32)fb.__x << 8);
#endif
}
template<bool HI>
__device__ inline f2_t upk_fp8(u32 w){
#if __has_builtin(__builtin_amdgcn_cvt_pk_f32_fp8)
  return __builtin_amdgcn_cvt_pk_f32_fp8(w, HI);
#else
  const u32 hh = HI ? (w >> 16) : (w & 0xFFFFu);
  __hip_fp8_e4m3 a, b;
  a.__x = (unsigned char)(hh & 0xFF);
  b.__x = (unsigned char)(hh >> 8);
  return (f2_t){(float)a, (float)b};
#endif
}
// load 8 f32 weights and pack to bf16x8
__device__ inline s16x8 ldw8(const float* __restrict__ src){
  const f4_t v0 = *(const f4_t*)src;
  const f4_t v1 = *(const f4_t*)(src + 4);
  s16x8 o = { f2bf(v0[0]), f2bf(v0[1]), f2bf(v0[2]), f2bf(v0[3]),
              f2bf(v1[0]), f2bf(v1[1]), f2bf(v1[2]), f2bf(v1[3]) };
  return o;
}

// =============== K1: fused projection GEMM (uniform BM=32, 3 blocks/CU) =========
// bid < 1024: value-proj tile (BM=32) -> fp8 gather layout vfp8 (Cs-transposed)
// bid >= 1024: offset/logit tile (BM=32) -> offw/logit f32
// LDS: As 16KB + Bs 32KB + Cs 2KB = 50KB -> 3 blocks/CU (was 68KB -> 2).
__global__ __launch_bounds__(256, 2) void k_proj(const float* __restrict__ value,
    const float* __restrict__ query, const float* __restrict__ Wval,
    const float* __restrict__ Woff, const float* __restrict__ Wattn,
    const float* __restrict__ bval, const float* __restrict__ boff,
    const float* __restrict__ battn, char* __restrict__ vfp8,
    float* __restrict__ offw, float* __restrict__ logit){
  __shared__ short As[32 * 256];
  __shared__ short Bs[64 * 256];
  __shared__ u32 Cs[512];                     // 2KB fp8 transpose (val path)
  const int tid = threadIdx.x;
  const int lane = tid & 63, wv = tid >> 6;
  const int r16 = lane & 15, kh = lane >> 4;
  const int mg = wv & 1, ch = wv >> 1;
  const int swsel = (r16 & 7) << 4;
  const int bid = blockIdx.x;

  if (bid < 1024){
    // ---------------- value-projection path (BM=32) ----------------
    const int mbase = bid * 32;
    #pragma unroll
    for (int i = 0; i < 8; ++i){
      const int lin = i * 256 + tid;
      const int r = lin >> 6, ck = lin & 63;
      const f4_t v = *(const f4_t*)(value + (size_t)(mbase + r) * DK + ck * 4);
      s16x4 o = { f2bf(v[0]), f2bf(v[1]), f2bf(v[2]), f2bf(v[3]) };
      *(s16x4*)((char*)As + r * 512 + ((ck * 8) ^ ((r & 7) << 4))) = o;
    }
    s16x8 breg[8];
    #pragma unroll
    for (int i = 0; i < 8; ++i){
      const int lin = i * 256 + tid;
      const int n = lin >> 5, ck = lin & 31;
      breg[i] = ldw8(Wval + (size_t)n * DK + ck * 8);
    }
    __syncthreads();
    for (int cg = 0; cg < 4; ++cg){
      #pragma unroll
      for (int i = 0; i < 8; ++i){
        const int lin = i * 256 + tid;
        const int n = lin >> 5, ck = lin & 31;
        *(s16x8*)((char*)Bs + n * 512 + ((ck * 16) ^ ((n & 7) << 4))) = breg[i];
      }
      __syncthreads();
      if (cg < 3){
        #pragma unroll
        for (int i = 0; i < 8; ++i){
          const int lin = i * 256 + tid;
          const int n = lin >> 5, ck = lin & 31;
          breg[i] = ldw8(Wval + (size_t)((cg + 1) * 64 + n) * DK + ck * 8);
        }
      }
      f4_t acc[2];
      acc[0] = (f4_t){0.f,0.f,0.f,0.f}; acc[1] = (f4_t){0.f,0.f,0.f,0.f};
      #pragma unroll
      for (int kk = 0; kk < 8; ++kk){
        const int kb = kh * 16 + kk * 64;
        const s16x8 a = *(const s16x8*)((char*)As + (mg * 16 + r16) * 512 + (kb ^ swsel));
        #pragma unroll
        for (int nt = 0; nt < 2; ++nt){
          const s16x8 b = *(const s16x8*)((char*)Bs + (ch * 32 + nt * 16 + r16) * 512 + (kb ^ swsel));
          acc[nt] = __builtin_amdgcn_mfma_f32_16x16x32_bf16(a, b, acc[nt], 0, 0, 0);
        }
      }
      // epilogue: f32 -> fp8 into Cs[32 rows][64 col-bytes], then coalesced out
      #pragma unroll
      for (int nt = 0; nt < 2; ++nt){
        const int cb = ch * 32 + nt * 16 + r16;       // col byte in group
        const float bv = bval[cg * 64 + cb];
        #pragma unroll
        for (int rix = 0; rix < 4; ++rix){
          const float vv = acc[nt][rix] + bv;
          ((char*)Cs)[(mg * 16 + kh * 4 + rix) * 64 + cb] =
              (char)(pk_fp8(vv, 0.f) & 0xFFu);
        }
      }
      __syncthreads();                          // Cs ready; also fences Bs reads
      {
        const u32x2 cw = *((const u32x2*)((const char*)Cs + tid * 8));
        const int row = tid >> 3, c8 = tid & 7;
        const int h2 = cg * 2 + (c8 >> 2);
        const int m = mbase + row;
        const int r = m >> 14, pix = m & (QN - 1);
        *(u32x2*)(vfp8 + ((size_t)((r * 8 + h2) * QN + pix)) * 32 + (c8 & 3) * 8) = cw;
      }
      __syncthreads();                          // Cs free before next epilogue
    }
  } else {
    // ---------------- offset/logit path (BM=32) ----------------
    const int mbase = (bid - 1024) * 32;
    #pragma unroll
    for (int i = 0; i < 8; ++i){
      const int lin = i * 256 + tid;
      const int r = lin >> 6, ck = lin & 63;
      const f4_t v = *(const f4_t*)(query + (size_t)(mbase + r) * DK + ck * 4);
      s16x4 o = { f2bf(v[0]), f2bf(v[1]), f2bf(v[2]), f2bf(v[3]) };
      *(s16x4*)((char*)As + r * 512 + ((ck * 8) ^ ((r & 7) << 4))) = o;
    }
    s16x8 breg[8];
    #pragma unroll
    for (int i = 0; i < 8; ++i){
      const int lin = i * 256 + tid;
      const int n = lin >> 5, ck = lin & 31;
      breg[i] = ldw8(Woff + (size_t)n * DK + ck * 8);
    }
    __syncthreads();
    for (int cg = 0; cg < 3; ++cg){
      #pragma unroll
      for (int i = 0; i < 8; ++i){
        const int lin = i * 256 + tid;
        const int n = lin >> 5, ck = lin & 31;
        *(s16x8*)((char*)Bs + n * 512 + ((ck * 16) ^ ((n & 7) << 4))) = breg[i];
      }
      __syncthreads();
      if (cg < 2){
        #pragma unroll
        for (int i = 0; i < 8; ++i){
          const int lin = i * 256 + tid;
          const int n = lin >> 5, ck = lin & 31;
          const int rrow = (cg + 1) * 64 + n;     // [64,192)
          const float* src = (rrow < 128) ? (Woff  + (size_t)rrow * DK)
                                          : (Wattn + (size_t)(rrow - 128) * DK);
          breg[i] = ldw8(src + ck * 8);
        }
      }
      f4_t acc[2];
      acc[0] = (f4_t){0.f,0.f,0.f,0.f}; acc[1] = (f4_t){0.f,0.f,0.f,0.f};
      #pragma unroll
      for (int kk = 0; kk < 8; ++kk){
        const int kb = kh * 16 + kk * 64;
        const s16x8 a = *(const s16x8*)((char*)As + (mg * 16 + r16) * 512 + (kb ^ swsel));
        #pragma unroll
        for (int nt = 0; nt < 2; ++nt){
          const s16x8 b = *(const s16x8*)((char*)Bs + (ch * 32 + nt * 16 + r16) * 512 + (kb ^ swsel));
          acc[nt] = __builtin_amdgcn_mfma_f32_16x16x32_bf16(a, b, acc[nt], 0, 0, 0);
        }
      }
      #pragma unroll
      for (int nt = 0; nt < 2; ++nt){
        const int n = cg * 64 + ch * 32 + nt * 16 + r16;
        #pragma unroll
        for (int rix = 0; rix < 4; ++rix){
          const int m = mbase + mg * 16 + kh * 4 + rix;
          const float v = acc[nt][rix];
          if (n < 128) offw[(size_t)m * 128 + n] = v + boff[n];
          else         logit[(size_t)m * 64 + (n - 128)] = v + battn[n - 128];
        }
      }
      __syncthreads();
    }
  }
}

// =============== K4: output projection + bias + residual, BM=32 =================
__global__ __launch_bounds__(256, 2) void k_gemm_out(const short* __restrict__ Ab,
    const float* __restrict__ Wout, const float* __restrict__ bout,
    const float* __restrict__ query, float* __restrict__ out){
  __shared__ short As[32 * 256];
  __shared__ short Bs[64 * 256];
  const int tid = threadIdx.x;
  const int lane = tid & 63, wv = tid >> 6;
  const int r16 = lane & 15, kh = lane >> 4;
  const int mg = wv & 1, ch = wv >> 1;
  const int swsel = (r16 & 7) << 4;
  const int mbase = blockIdx.x * 32;

  #pragma unroll
  for (int i = 0; i < 4; ++i){
    const int lin = i * 256 + tid;
    const int r = lin >> 5, ck = lin & 31;
    const s16x8 v = *(const s16x8*)(Ab + (size_t)(mbase + r) * DK + ck * 8);
    *(s16x8*)((char*)As + r * 512 + ((ck * 16) ^ ((r & 7) << 4))) = v;
  }
  s16x8 breg[8];
  #pragma unroll
  for (int i = 0; i < 8; ++i){
    const int lin = i * 256 + tid;
    const int n = lin >> 5, ck = lin & 31;
    breg[i] = ldw8(Wout + (size_t)n * DK + ck * 8);
  }
  __syncthreads();

  for (int cg = 0; cg < 4; ++cg){
    #pragma unroll
    for (int i = 0; i < 8; ++i){
      const int lin = i * 256 + tid;
      const int n = lin >> 5, ck = lin & 31;
      *(s16x8*)((char*)Bs + n * 512 + ((ck * 16) ^ ((n & 7) << 4))) = breg[i];
    }
    __syncthreads();
    if (cg < 3){
      #pragma unroll
      for (int i = 0; i < 8; ++i){
        const int lin = i * 256 + tid;
        const int n = lin >> 5, ck = lin & 31;
        breg[i] = ldw8(Wout + (size_t)((cg + 1) * 64 + n) * DK + ck * 8);
      }
    }
    f4_t acc[2];
    acc[0] = (f4_t){0.f,0.f,0.f,0.f}; acc[1] = (f4_t){0.f,0.f,0.f,0.f};
    #pragma unroll
    for (int kk = 0; kk < 8; ++kk){
      const int kb = kh * 16 + kk * 64;
      const s16x8 a = *(const s16x8*)((char*)As + (mg * 16 + r16) * 512 + (kb ^ swsel));
      #pragma unroll
      for (int nt = 0; nt < 2; ++nt){
        const s16x8 b = *(const s16x8*)((char*)Bs + (ch * 32 + nt * 16 + r16) * 512 + (kb ^ swsel));
        acc[nt] = __builtin_amdgcn_mfma_f32_16x16x32_bf16(a, b, acc[nt], 0, 0, 0);
      }
    }
    #pragma unroll
    for (int nt = 0; nt < 2; ++nt){
      const int n = cg * 64 + ch * 32 + nt * 16 + r16;
      const float bo = bout[n];
      #pragma unroll
      for (int rix = 0; rix < 4; ++rix){
        const int m = mbase + mg * 16 + kh * 4 + rix;
        out[(size_t)m * DK + n] = acc[nt][rix] + bo + query[(size_t)m * DK + n];
      }
    }
    __syncthreads();
  }
}

// ---------------- K3: bilinear sampling, fp8 v-cache, 16B-per-lane loads --------
__device__ inline void mkw(float rx, float ry, float ox, float oy, float awp,
                           u32& word, u32& pk01, u32& pk23){
  const float x = fmaf(rx, 128.f, ox) - 0.5f;
  const float y = fmaf(ry, 128.f, oy) - 0.5f;
  const float xf = floorf(x), yf = floorf(y);
  const float wx = x - xf, wy = y - yf;
  const int ix = (int)xf, iy = (int)yf;
  float xw0 = 1.f - wx, xw1 = wx, yw0 = 1.f - wy, yw1 = wy;
  if (ix < 0 || ix > 127)   xw0 = 0.f;
  if (ix < -1 || ix > 126)  xw1 = 0.f;
  if (iy < 0 || iy > 127)   yw0 = 0.f;
  if (iy < -1 || iy > 126)  yw1 = 0.f;
  const int ix0 = min(max(ix, 0), 127), ix1 = min(max(ix + 1, 0), 127);
  const int iy0 = min(max(iy, 0), 127), iy1 = min(max(iy + 1, 0), 127);
  const float t0 = awp * yw0, t1 = awp * yw1;
  pk01 = pk2h(t0 * xw0, t0 * xw1);     // (row0: x0-w, x1-w) fp16
  pk23 = pk2h(t1 * xw0, t1 * xw1);     // (row1: x0-w, x1-w) fp16
  word = (u32)(iy0 * 128 + ix0) | ((u32)(ix1 - ix0) << 16) | ((u32)(iy1 - iy0) << 17);
}

__global__ __launch_bounds__(256) void k_sampler(const float* __restrict__ rp,
    const float* __restrict__ offw, const float* __restrict__ logit,
    const char* __restrict__ vfp8, short* __restrict__ O2b){
  const int tid = threadIdx.x;
  const int j3 = tid & 7;               // lane in group
  const int row2 = j3 >> 2;             // row (y0 / y1)
  const int px2 = (j3 >> 1) & 1;        // pixel side (x0 / x1)
  const int ck2 = j3 & 1;               // channel half: [16*ck2, 16*ck2+16)
  const int grp = tid >> 3;             // query in block: 0..31
  const int lane = tid & 63;
  const int glane8 = lane & ~7;
  const int h = blockIdx.x & 7;
  const int q = (blockIdx.x >> 3) * 32 + grp;
  const u32 laneof = (u32)ck2 * 16;     // byte offset of my channel half

  const float* lp = logit + (size_t)q * 64 + h * 8;
  const float l = lp[j3];
  float m = l;
  m = fmaxf(m, __shfl_xor(m, 1)); m = fmaxf(m, __shfl_xor(m, 2)); m = fmaxf(m, __shfl_xor(m, 4));
  const float e = __expf(l - m);
  float ssum = e;
  ssum += __shfl_xor(ssum, 1); ssum += __shfl_xor(ssum, 2); ssum += __shfl_xor(ssum, 4);
  const float awp = e * (0.5f / ssum);

  const float* offp = offw + (size_t)q * 128 + h * 16;
  const float ox = offp[2 * j3], oy = offp[2 * j3 + 1];
  const int za2 = (j3 & 3) * 2;
  const float rx0 = rp[(size_t)q * 8 + za2],        ry0 = rp[(size_t)q * 8 + za2 + 1];
  const float rx1 = rp[(size_t)(QN + q) * 8 + za2], ry1 = rp[(size_t)(QN + q) * 8 + za2 + 1];

  u32 wrdA, pkA01, pkA23, wrdB, pkB01, pkB23;
  mkw(rx0, ry0, ox, oy, awp, wrdA, pkA01, pkA23);   // r=0 sample (owner: lane j3 = p)
  mkw(rx1, ry1, ox, oy, awp, wrdB, pkB01, pkB23);   // r=1 sample

  const char* vb0 = vfp8 + (size_t)(h * QN) * 32;
  const char* vb1 = vfp8 + (size_t)((8 + h) * QN) * 32;

  float acc[16];
  #pragma unroll
  for (int i = 0; i < 16; ++i) acc[i] = 0.f;

#define LOADP(S, WRD, VB)                                                   \
  const u32 wd_##S = __shfl((WRD), glane8 | ((S) & 7));                     \
  const u32 ad_##S = (wd_##S & 0xFFFFu) * 32u + laneof                      \
                   + (px2 ? ((wd_##S >> 11) & 32u) : 0u)                    \
                   + (row2 ? ((wd_##S >> 17) & 1u) * 4096u : 0u);           \
  const u32x4 c_##S = *(const u32x4*)((VB) + ad_##S);

#define USEP(S, PK01, PK23) do{                                             \
    const int srcl_ = glane8 | ((S) & 7);                                   \
    const u32 w01_ = __shfl((PK01), srcl_);                                 \
    const u32 w23_ = __shfl((PK23), srcl_);                                 \
    const u32 wsel_ = row2 ? w23_ : w01_;                                   \
    const h2_t wh_ = __builtin_bit_cast(h2_t, wsel_);                       \
    const float w_ = px2 ? (float)wh_[1] : (float)wh_[0];                   \
    _Pragma("unroll")                                                       \
    for (int i_ = 0; i_ < 4; ++i_){                                         \
      const f2_t lo_ = upk_fp8<false>(c_##S[i_]);                           \
      const f2_t hi_ = upk_fp8<true >(c_##S[i_]);                           \
      acc[4*i_+0] = fmaf(w_, lo_[0], acc[4*i_+0]);                          \
      acc[4*i_+1] = fmaf(w_, lo_[1], acc[4*i_+1]);                          \
      acc[4*i_+2] = fmaf(w_, hi_[0], acc[4*i_+2]);                          \
      acc[4*i_+3] = fmaf(w_, hi_[1], acc[4*i_+3]);                          \
    }                                                                       \
  }while(0)

  LOADP(0,  wrdA, vb0) LOADP(1,  wrdA, vb0) LOADP(2,  wrdA, vb0)
  USEP(0,  pkA01, pkA23); LOADP(3,  wrdA, vb0)
  USEP(1,  pkA01, pkA23); LOADP(4,  wrdA, vb0)
  USEP(2,  pkA01, pkA23); LOADP(5,  wrdA, vb0)
  USEP(3,  pkA01, pkA23); LOADP(6,  wrdA, vb0)
  USEP(4,  pkA01, pkA23); LOADP(7,  wrdA, vb0)
  USEP(5,  pkA01, pkA23); LOADP(8,  wrdB, vb1)
  USEP(6,  pkA01, pkA23); LOADP(9,  wrdB, vb1)
  USEP(7,  pkA01, pkA23); LOADP(10, wrdB, vb1)
  USEP(8,  pkB01, pkB23); LOADP(11, wrdB, vb1)
  USEP(9,  pkB01, pkB23); LOADP(12, wrdB, vb1)
  USEP(10, pkB01, pkB23); LOADP(13, wrdB, vb1)
  USEP(11, pkB01, pkB23); LOADP(14, wrdB, vb1)
  USEP(12, pkB01, pkB23); LOADP(15, wrdB, vb1)
  USEP(13, pkB01, pkB23);
  USEP(14, pkB01, pkB23);
  USEP(15, pkB01, pkB23);
#undef LOADP
#undef USEP

  #pragma unroll
  for (int i = 0; i < 16; ++i) acc[i] += __shfl_xor(acc[i], 4);
  #pragma unroll
  for (int i = 0; i < 16; ++i) acc[i] += __shfl_xor(acc[i], 2);
  if (j3 < 2){
    short* op = O2b + (size_t)q * DK + h * 32 + j3 * 16;
    s16x8 o0 = { f2bf(acc[0]),  f2bf(acc[1]),  f2bf(acc[2]),  f2bf(acc[3]),
                 f2bf(acc[4]),  f2bf(acc[5]),  f2bf(acc[6]),  f2bf(acc[7]) };
    s16x8 o1 = { f2bf(acc[8]),  f2bf(acc[9]),  f2bf(acc[10]), f2bf(acc[11]),
                 f2bf(acc[12]), f2bf(acc[13]), f2bf(acc[14]), f2bf(acc[15]) };
    *(s16x8*)op       = o0;
    *(s16x8*)(op + 8) = o1;
  }
}

extern "C" void kernel_launch(void* const* d_in, const int* in_sizes, int n_in,
                              void* d_out, int out_size, void* d_ws, size_t ws_size,
                              hipStream_t stream) {
  const float* query = (const float*)d_in[0];
  const float* value = (const float*)d_in[1];
  const float* refpt = (const float*)d_in[2];
  // d_in[3] spatial_shapes: fixed [[128,128]], hardcoded
  const float* W_off  = (const float*)d_in[4];
  const float* b_off  = (const float*)d_in[5];
  const float* W_attn = (const float*)d_in[6];
  const float* b_attn = (const float*)d_in[7];
  const float* W_val  = (const float*)d_in[8];
  const float* b_val  = (const float*)d_in[9];
  const float* W_out  = (const float*)d_in[10];
  const float* b_out  = (const float*)d_in[11];
  float* out = (float*)d_out;

  char* ws = (char*)d_ws;
  char*  vfp8 = (char*)(ws);                     // 2*8*16384*32 fp8      (8388608 B)
  float* offw = (float*)(ws + 8388608);          // 16384*128 f32         (8388608 B)
  float* logit= (float*)(ws + 16777216);         // 16384*64 f32          (4194304 B)
  short* O2b  = (short*)(ws + 20971520);         // 16384*256 bf16        (8388608 B)

  k_proj    <<<dim3(1536), dim3(256), 0, stream>>>(value, query, W_val, W_off, W_attn,
                                                   b_val, b_off, b_attn, vfp8, offw, logit);
  k_sampler <<<dim3(4096), dim3(256), 0, stream>>>(refpt, offw, logit, vfp8, O2b);
  k_gemm_out<<<dim3(512),  dim3(256), 0, stream>>>(O2b, W_out, b_out, query, out);
}

// Round 18
// 66.390 us; speedup vs baseline: 1.5510x; 1.1337x over previous
//
#include <hip/hip_runtime.h>
#include <hip/hip_bf16.h>
#include <hip/hip_fp16.h>
#include <hip/hip_fp8.h>

// Problem constants: B=1,R=2,D=256,NH=8,NP=8,ZA=4,H=W=128,Q=16384,HD=32
#define QN 16384
#define DK 256

typedef float f4_t __attribute__((ext_vector_type(4)));
typedef float f2_t __attribute__((ext_vector_type(2)));
typedef short s16x8 __attribute__((ext_vector_type(8)));
typedef short s16x4 __attribute__((ext_vector_type(4)));
typedef unsigned int u32;
typedef u32 u32x4 __attribute__((ext_vector_type(4)));
typedef u32 u32x2 __attribute__((ext_vector_type(2)));
typedef __fp16 h2_t __attribute__((ext_vector_type(2)));

__device__ inline short f2bf(float f){
  __hip_bfloat16 h = __float2bfloat16(f);
  return __builtin_bit_cast(short, h);
}
__device__ inline u32 pk2h(float a, float b){
#if __has_builtin(__builtin_amdgcn_cvt_pkrtz)
  h2_t r = __builtin_amdgcn_cvt_pkrtz(a, b);
  return __builtin_bit_cast(u32, r);
#else
  return (u32)__builtin_bit_cast(unsigned short, __float2half(a)) |
         ((u32)__builtin_bit_cast(unsigned short, __float2half(b)) << 16);
#endif
}
// fp8 e4m3 pack (2 floats -> low 16 bits) / unpack (HI = immediate template arg)
__device__ inline u32 pk_fp8(float a, float b){
#if __has_builtin(__builtin_amdgcn_cvt_pk_fp8_f32)
  return (u32)__builtin_amdgcn_cvt_pk_fp8_f32(a, b, 0, false);
#else
  __hip_fp8_e4m3 fa(a), fb(b);
  return (u32)fa.__x | ((u32)fb.__x << 8);
#endif
}
template<bool HI>
__device__ inline f2_t upk_fp8(u32 w){
#if __has_builtin(__builtin_amdgcn_cvt_pk_f32_fp8)
  return __builtin_amdgcn_cvt_pk_f32_fp8(w, HI);
#else
  const u32 hh = HI ? (w >> 16) : (w & 0xFFFFu);
  __hip_fp8_e4m3 a, b;
  a.__x = (unsigned char)(hh & 0xFF);
  b.__x = (unsigned char)(hh >> 8);
  return (f2_t){(float)a, (float)b};
#endif
}
// load 8 f32 weights and pack to bf16x8
__device__ inline s16x8 ldw8(const float* __restrict__ src){
  const f4_t v0 = *(const f4_t*)src;
  const f4_t v1 = *(const f4_t*)(src + 4);
  s16x8 o = { f2bf(v0[0]), f2bf(v0[1]), f2bf(v0[2]), f2bf(v0[3]),
              f2bf(v1[0]), f2bf(v1[1]), f2bf(v1[2]), f2bf(v1[3]) };
  return o;
}

// =============== K1: fused projection GEMM, 512-thread blocks ===================
// bid < 256:  value-proj tile (BM=128, 8 waves) -> fp8 vfp8 (Cs-transposed)
// bid >= 256: offset/logit tile (BM=64, 8 waves) -> offw/logit f32
// B-panel staged per cg as in R13; BM doubled -> B-staging/output halved.
__global__ __launch_bounds__(512, 2) void k_proj(const float* __restrict__ value,
    const float* __restrict__ query, const float* __restrict__ Wval,
    const float* __restrict__ Woff, const float* __restrict__ Wattn,
    const float* __restrict__ bval, const float* __restrict__ boff,
    const float* __restrict__ battn, char* __restrict__ vfp8,
    float* __restrict__ offw, float* __restrict__ logit){
  __shared__ short As[128 * 256];               // 64KB
  __shared__ short Bs[64 * 256];                // 32KB
  __shared__ u32 Cs[2048];                      // 8KB fp8 transpose (val path)
  const int tid = threadIdx.x;
  const int lane = tid & 63, wv = tid >> 6;     // wv 0..7
  const int r16 = lane & 15, kh = lane >> 4;
  const int swsel = (r16 & 7) << 4;
  const int bid = blockIdx.x;

  if (bid < 256){
    // ---------------- value-projection path (BM=128) ----------------
    const int mbase = bid * 128;
    #pragma unroll
    for (int i = 0; i < 16; ++i){
      const int lin = i * 512 + tid;            // 128 rows x 64 chunks
      const int r = lin >> 6, ck = lin & 63;
      const f4_t v = *(const f4_t*)(value + (size_t)(mbase + r) * DK + ck * 4);
      s16x4 o = { f2bf(v[0]), f2bf(v[1]), f2bf(v[2]), f2bf(v[3]) };
      *(s16x4*)((char*)As + r * 512 + ((ck * 8) ^ ((r & 7) << 4))) = o;
    }
    s16x8 breg[4];
    #pragma unroll
    for (int i = 0; i < 4; ++i){
      const int lin = i * 512 + tid;            // 64 rows x 32 chunks
      const int n = lin >> 5, ck = lin & 31;
      breg[i] = ldw8(Wval + (size_t)n * DK + ck * 8);
    }
    __syncthreads();
    for (int cg = 0; cg < 4; ++cg){
      #pragma unroll
      for (int i = 0; i < 4; ++i){
        const int lin = i * 512 + tid;
        const int n = lin >> 5, ck = lin & 31;
        *(s16x8*)((char*)Bs + n * 512 + ((ck * 16) ^ ((n & 7) << 4))) = breg[i];
      }
      __syncthreads();
      if (cg < 3){
        #pragma unroll
        for (int i = 0; i < 4; ++i){
          const int lin = i * 512 + tid;
          const int n = lin >> 5, ck = lin & 31;
          breg[i] = ldw8(Wval + (size_t)((cg + 1) * 64 + n) * DK + ck * 8);
        }
      }
      f4_t acc[4];
      #pragma unroll
      for (int i = 0; i < 4; ++i) acc[i] = (f4_t){0.f, 0.f, 0.f, 0.f};
      #pragma unroll
      for (int kk = 0; kk < 8; ++kk){
        const int kb = kh * 16 + kk * 64;
        const s16x8 a = *(const s16x8*)((char*)As + (wv * 16 + r16) * 512 + (kb ^ swsel));
        #pragma unroll
        for (int nt = 0; nt < 4; ++nt){
          const s16x8 b = *(const s16x8*)((char*)Bs + (nt * 16 + r16) * 512 + (kb ^ swsel));
          acc[nt] = __builtin_amdgcn_mfma_f32_16x16x32_bf16(a, b, acc[nt], 0, 0, 0);
        }
      }
      // epilogue: f32 -> fp8, Cs[128 rows][64 col-bytes], coalesced 16B stores
      #pragma unroll
      for (int nt = 0; nt < 4; ++nt){
        const int n = cg * 64 + nt * 16 + r16;
        const float bv = bval[n];
        #pragma unroll
        for (int rix = 0; rix < 4; ++rix){
          const float vv = acc[nt][rix] + bv;
          ((char*)Cs)[(wv * 16 + kh * 4 + rix) * 64 + nt * 16 + r16] =
              (char)(pk_fp8(vv, 0.f) & 0xFFu);
        }
      }
      __syncthreads();                          // Cs ready; also fences Bs reads
      {
        const u32x4 cw = *((const u32x4*)((const char*)Cs + tid * 16));
        const int row = tid >> 2, q4 = tid & 3;
        const int h2 = cg * 2 + (q4 >> 1);
        const int m = mbase + row;
        const int r = m >> 14, pix = m & (QN - 1);
        *(u32x4*)(vfp8 + ((size_t)((r * 8 + h2) * QN + pix)) * 32 + (q4 & 1) * 16) = cw;
      }
    }
  } else {
    // ---------------- offset/logit path (BM=64) ----------------
    const int mg = wv >> 1, ch = wv & 1;        // 4 m-groups x 2 col-halves
    const int mbase = (bid - 256) * 64;
    #pragma unroll
    for (int i = 0; i < 8; ++i){
      const int lin = i * 512 + tid;            // 64 rows x 64 chunks
      const int r = lin >> 6, ck = lin & 63;
      const f4_t v = *(const f4_t*)(query + (size_t)(mbase + r) * DK + ck * 4);
      s16x4 o = { f2bf(v[0]), f2bf(v[1]), f2bf(v[2]), f2bf(v[3]) };
      *(s16x4*)((char*)As + r * 512 + ((ck * 8) ^ ((r & 7) << 4))) = o;
    }
    s16x8 breg[4];
    #pragma unroll
    for (int i = 0; i < 4; ++i){
      const int lin = i * 512 + tid;
      const int n = lin >> 5, ck = lin & 31;
      breg[i] = ldw8(Woff + (size_t)n * DK + ck * 8);
    }
    __syncthreads();
    for (int cg = 0; cg < 3; ++cg){
      #pragma unroll
      for (int i = 0; i < 4; ++i){
        const int lin = i * 512 + tid;
        const int n = lin >> 5, ck = lin & 31;
        *(s16x8*)((char*)Bs + n * 512 + ((ck * 16) ^ ((n & 7) << 4))) = breg[i];
      }
      __syncthreads();
      if (cg < 2){
        #pragma unroll
        for (int i = 0; i < 4; ++i){
          const int lin = i * 512 + tid;
          const int n = lin >> 5, ck = lin & 31;
          const int rrow = (cg + 1) * 64 + n;     // [64,192)
          const float* src = (rrow < 128) ? (Woff  + (size_t)rrow * DK)
                                          : (Wattn + (size_t)(rrow - 128) * DK);
          breg[i] = ldw8(src + ck * 8);
        }
      }
      f4_t acc[2];
      acc[0] = (f4_t){0.f,0.f,0.f,0.f}; acc[1] = (f4_t){0.f,0.f,0.f,0.f};
      #pragma unroll
      for (int kk = 0; kk < 8; ++kk){
        const int kb = kh * 16 + kk * 64;
        const s16x8 a = *(const s16x8*)((char*)As + (mg * 16 + r16) * 512 + (kb ^ swsel));
        #pragma unroll
        for (int nt = 0; nt < 2; ++nt){
          const s16x8 b = *(const s16x8*)((char*)Bs + (ch * 32 + nt * 16 + r16) * 512 + (kb ^ swsel));
          acc[nt] = __builtin_amdgcn_mfma_f32_16x16x32_bf16(a, b, acc[nt], 0, 0, 0);
        }
      }
      #pragma unroll
      for (int nt = 0; nt < 2; ++nt){
        const int n = cg * 64 + ch * 32 + nt * 16 + r16;
        #pragma unroll
        for (int rix = 0; rix < 4; ++rix){
          const int m = mbase + mg * 16 + kh * 4 + rix;
          const float v = acc[nt][rix];
          if (n < 128) offw[(size_t)m * 128 + n] = v + boff[n];
          else         logit[(size_t)m * 64 + (n - 128)] = v + battn[n - 128];
        }
      }
      __syncthreads();
    }
  }
}

// =============== K4: output projection + bias + residual, BM=32 (R13) ===========
__global__ __launch_bounds__(256, 2) void k_gemm_out(const short* __restrict__ Ab,
    const float* __restrict__ Wout, const float* __restrict__ bout,
    const float* __restrict__ query, float* __restrict__ out){
  __shared__ short As[32 * 256];
  __shared__ short Bs[64 * 256];
  const int tid = threadIdx.x;
  const int lane = tid & 63, wv = tid >> 6;
  const int r16 = lane & 15, kh = lane >> 4;
  const int mg = wv & 1, ch = wv >> 1;
  const int swsel = (r16 & 7) << 4;
  const int mbase = blockIdx.x * 32;

  #pragma unroll
  for (int i = 0; i < 4; ++i){
    const int lin = i * 256 + tid;
    const int r = lin >> 5, ck = lin & 31;
    const s16x8 v = *(const s16x8*)(Ab + (size_t)(mbase + r) * DK + ck * 8);
    *(s16x8*)((char*)As + r * 512 + ((ck * 16) ^ ((r & 7) << 4))) = v;
  }
  s16x8 breg[8];
  #pragma unroll
  for (int i = 0; i < 8; ++i){
    const int lin = i * 256 + tid;
    const int n = lin >> 5, ck = lin & 31;
    breg[i] = ldw8(Wout + (size_t)n * DK + ck * 8);
  }
  __syncthreads();

  for (int cg = 0; cg < 4; ++cg){
    #pragma unroll
    for (int i = 0; i < 8; ++i){
      const int lin = i * 256 + tid;
      const int n = lin >> 5, ck = lin & 31;
      *(s16x8*)((char*)Bs + n * 512 + ((ck * 16) ^ ((n & 7) << 4))) = breg[i];
    }
    __syncthreads();
    if (cg < 3){
      #pragma unroll
      for (int i = 0; i < 8; ++i){
        const int lin = i * 256 + tid;
        const int n = lin >> 5, ck = lin & 31;
        breg[i] = ldw8(Wout + (size_t)((cg + 1) * 64 + n) * DK + ck * 8);
      }
    }
    f4_t acc[2];
    acc[0] = (f4_t){0.f,0.f,0.f,0.f}; acc[1] = (f4_t){0.f,0.f,0.f,0.f};
    #pragma unroll
    for (int kk = 0; kk < 8; ++kk){
      const int kb = kh * 16 + kk * 64;
      const s16x8 a = *(const s16x8*)((char*)As + (mg * 16 + r16) * 512 + (kb ^ swsel));
      #pragma unroll
      for (int nt = 0; nt < 2; ++nt){
        const s16x8 b = *(const s16x8*)((char*)Bs + (ch * 32 + nt * 16 + r16) * 512 + (kb ^ swsel));
        acc[nt] = __builtin_amdgcn_mfma_f32_16x16x32_bf16(a, b, acc[nt], 0, 0, 0);
      }
    }
    #pragma unroll
    for (int nt = 0; nt < 2; ++nt){
      const int n = cg * 64 + ch * 32 + nt * 16 + r16;
      const float bo = bout[n];
      #pragma unroll
      for (int rix = 0; rix < 4; ++rix){
        const int m = mbase + mg * 16 + kh * 4 + rix;
        out[(size_t)m * DK + n] = acc[nt][rix] + bo + query[(size_t)m * DK + n];
      }
    }
    __syncthreads();
  }
}

// ---------------- K3: bilinear sampling (EXACT R13) -----------------------------
__device__ inline void mkw(float rx, float ry, float ox, float oy, float awp,
                           u32& word, u32& pk01, u32& pk23){
  const float x = fmaf(rx, 128.f, ox) - 0.5f;
  const float y = fmaf(ry, 128.f, oy) - 0.5f;
  const float xf = floorf(x), yf = floorf(y);
  const float wx = x - xf, wy = y - yf;
  const int ix = (int)xf, iy = (int)yf;
  float xw0 = 1.f - wx, xw1 = wx, yw0 = 1.f - wy, yw1 = wy;
  if (ix < 0 || ix > 127)   xw0 = 0.f;
  if (ix < -1 || ix > 126)  xw1 = 0.f;
  if (iy < 0 || iy > 127)   yw0 = 0.f;
  if (iy < -1 || iy > 126)  yw1 = 0.f;
  const int ix0 = min(max(ix, 0), 127), ix1 = min(max(ix + 1, 0), 127);
  const int iy0 = min(max(iy, 0), 127), iy1 = min(max(iy + 1, 0), 127);
  const float t0 = awp * yw0, t1 = awp * yw1;
  pk01 = pk2h(t0 * xw0, t0 * xw1);     // (row0: x0-w, x1-w) fp16
  pk23 = pk2h(t1 * xw0, t1 * xw1);     // (row1: x0-w, x1-w) fp16
  word = (u32)(iy0 * 128 + ix0) | ((u32)(ix1 - ix0) << 16) | ((u32)(iy1 - iy0) << 17);
}

__global__ __launch_bounds__(256) void k_sampler(const float* __restrict__ rp,
    const float* __restrict__ offw, const float* __restrict__ logit,
    const char* __restrict__ vfp8, short* __restrict__ O2b){
  const int tid = threadIdx.x;
  const int j3 = tid & 7;               // lane in group
  const int row2 = j3 >> 2;             // row (y0 / y1)
  const int px2 = (j3 >> 1) & 1;        // pixel side (x0 / x1)
  const int ck2 = j3 & 1;               // channel half: [16*ck2, 16*ck2+16)
  const int grp = tid >> 3;             // query in block: 0..31
  const int lane = tid & 63;
  const int glane8 = lane & ~7;
  const int h = blockIdx.x & 7;
  const int q = (blockIdx.x >> 3) * 32 + grp;
  const u32 laneof = (u32)ck2 * 16;     // byte offset of my channel half

  const float* lp = logit + (size_t)q * 64 + h * 8;
  const float l = lp[j3];
  float m = l;
  m = fmaxf(m, __shfl_xor(m, 1)); m = fmaxf(m, __shfl_xor(m, 2)); m = fmaxf(m, __shfl_xor(m, 4));
  const float e = __expf(l - m);
  float ssum = e;
  ssum += __shfl_xor(ssum, 1); ssum += __shfl_xor(ssum, 2); ssum += __shfl_xor(ssum, 4);
  const float awp = e * (0.5f / ssum);

  const float* offp = offw + (size_t)q * 128 + h * 16;
  const float ox = offp[2 * j3], oy = offp[2 * j3 + 1];
  const int za2 = (j3 & 3) * 2;
  const float rx0 = rp[(size_t)q * 8 + za2],        ry0 = rp[(size_t)q * 8 + za2 + 1];
  const float rx1 = rp[(size_t)(QN + q) * 8 + za2], ry1 = rp[(size_t)(QN + q) * 8 + za2 + 1];

  u32 wrdA, pkA01, pkA23, wrdB, pkB01, pkB23;
  mkw(rx0, ry0, ox, oy, awp, wrdA, pkA01, pkA23);   // r=0 sample (owner: lane j3 = p)
  mkw(rx1, ry1, ox, oy, awp, wrdB, pkB01, pkB23);   // r=1 sample

  const char* vb0 = vfp8 + (size_t)(h * QN) * 32;
  const char* vb1 = vfp8 + (size_t)((8 + h) * QN) * 32;

  float acc[16];
  #pragma unroll
  for (int i = 0; i < 16; ++i) acc[i] = 0.f;

#define LOADP(S, WRD, VB)                                                   \
  const u32 wd_##S = __shfl((WRD), glane8 | ((S) & 7));                     \
  const u32 ad_##S = (wd_##S & 0xFFFFu) * 32u + laneof                      \
                   + (px2 ? ((wd_##S >> 11) & 32u) : 0u)                    \
                   + (row2 ? ((wd_##S >> 17) & 1u) * 4096u : 0u);           \
  const u32x4 c_##S = *(const u32x4*)((VB) + ad_##S);

#define USEP(S, PK01, PK23) do{                                             \
    const int srcl_ = glane8 | ((S) & 7);                                   \
    const u32 w01_ = __shfl((PK01), srcl_);                                 \
    const u32 w23_ = __shfl((PK23), srcl_);                                 \
    const u32 wsel_ = row2 ? w23_ : w01_;                                   \
    const h2_t wh_ = __builtin_bit_cast(h2_t, wsel_);                       \
    const float w_ = px2 ? (float)wh_[1] : (float)wh_[0];                   \
    _Pragma("unroll")                                                       \
    for (int i_ = 0; i_ < 4; ++i_){                                         \
      const f2_t lo_ = upk_fp8<false>(c_##S[i_]);                           \
      const f2_t hi_ = upk_fp8<true >(c_##S[i_]);                           \
      acc[4*i_+0] = fmaf(w_, lo_[0], acc[4*i_+0]);                          \
      acc[4*i_+1] = fmaf(w_, lo_[1], acc[4*i_+1]);                          \
      acc[4*i_+2] = fmaf(w_, hi_[0], acc[4*i_+2]);                          \
      acc[4*i_+3] = fmaf(w_, hi_[1], acc[4*i_+3]);                          \
    }                                                                       \
  }while(0)

  LOADP(0,  wrdA, vb0) LOADP(1,  wrdA, vb0) LOADP(2,  wrdA, vb0)
  USEP(0,  pkA01, pkA23); LOADP(3,  wrdA, vb0)
  USEP(1,  pkA01, pkA23); LOADP(4,  wrdA, vb0)
  USEP(2,  pkA01, pkA23); LOADP(5,  wrdA, vb0)
  USEP(3,  pkA01, pkA23); LOADP(6,  wrdA, vb0)
  USEP(4,  pkA01, pkA23); LOADP(7,  wrdA, vb0)
  USEP(5,  pkA01, pkA23); LOADP(8,  wrdB, vb1)
  USEP(6,  pkA01, pkA23); LOADP(9,  wrdB, vb1)
  USEP(7,  pkA01, pkA23); LOADP(10, wrdB, vb1)
  USEP(8,  pkB01, pkB23); LOADP(11, wrdB, vb1)
  USEP(9,  pkB01, pkB23); LOADP(12, wrdB, vb1)
  USEP(10, pkB01, pkB23); LOADP(13, wrdB, vb1)
  USEP(11, pkB01, pkB23); LOADP(14, wrdB, vb1)
  USEP(12, pkB01, pkB23); LOADP(15, wrdB, vb1)
  USEP(13, pkB01, pkB23);
  USEP(14, pkB01, pkB23);
  USEP(15, pkB01, pkB23);
#undef LOADP
#undef USEP

  #pragma unroll
  for (int i = 0; i < 16; ++i) acc[i] += __shfl_xor(acc[i], 4);
  #pragma unroll
  for (int i = 0; i < 16; ++i) acc[i] += __shfl_xor(acc[i], 2);
  if (j3 < 2){
    short* op = O2b + (size_t)q * DK + h * 32 + j3 * 16;
    s16x8 o0 = { f2bf(acc[0]),  f2bf(acc[1]),  f2bf(acc[2]),  f2bf(acc[3]),
                 f2bf(acc[4]),  f2bf(acc[5]),  f2bf(acc[6]),  f2bf(acc[7]) };
    s16x8 o1 = { f2bf(acc[8]),  f2bf(acc[9]),  f2bf(acc[10]), f2bf(acc[11]),
                 f2bf(acc[12]), f2bf(acc[13]), f2bf(acc[14]), f2bf(acc[15]) };
    *(s16x8*)op       = o0;
    *(s16x8*)(op + 8) = o1;
  }
}

extern "C" void kernel_launch(void* const* d_in, const int* in_sizes, int n_in,
                              void* d_out, int out_size, void* d_ws, size_t ws_size,
                              hipStream_t stream) {
  const float* query = (const float*)d_in[0];
  const float* value = (const float*)d_in[1];
  const float* refpt = (const float*)d_in[2];
  // d_in[3] spatial_shapes: fixed [[128,128]], hardcoded
  const float* W_off  = (const float*)d_in[4];
  const float* b_off  = (const float*)d_in[5];
  const float* W_attn = (const float*)d_in[6];
  const float* b_attn = (const float*)d_in[7];
  const float* W_val  = (const float*)d_in[8];
  const float* b_val  = (const float*)d_in[9];
  const float* W_out  = (const float*)d_in[10];
  const float* b_out  = (const float*)d_in[11];
  float* out = (float*)d_out;

  char* ws = (char*)d_ws;
  char*  vfp8 = (char*)(ws);                     // 2*8*16384*32 fp8      (8388608 B)
  float* offw = (float*)(ws + 8388608);          // 16384*128 f32         (8388608 B)
  float* logit= (float*)(ws + 16777216);         // 16384*64 f32          (4194304 B)
  short* O2b  = (short*)(ws + 20971520);         // 16384*256 bf16        (8388608 B)

  k_proj    <<<dim3(512),  dim3(512), 0, stream>>>(value, query, W_val, W_off, W_attn,
                                                   b_val, b_off, b_attn, vfp8, offw, logit);
  k_sampler <<<dim3(4096), dim3(256), 0, stream>>>(refpt, offw, logit, vfp8, O2b);
  k_gemm_out<<<dim3(512),  dim3(256), 0, stream>>>(O2b, W_out, b_out, query, out);
}

// Round 19
// 64.339 us; speedup vs baseline: 1.6004x; 1.0319x over previous
//
#include <hip/hip_runtime.h>
#include <hip/hip_bf16.h>
#include <hip/hip_fp16.h>
#include <hip/hip_fp8.h>

// Problem constants: B=1,R=2,D=256,NH=8,NP=8,ZA=4,H=W=128,Q=16384,HD=32
#define QN 16384
#define DK 256

typedef float f4_t __attribute__((ext_vector_type(4)));
typedef float f2_t __attribute__((ext_vector_type(2)));
typedef short s16x8 __attribute__((ext_vector_type(8)));
typedef short s16x4 __attribute__((ext_vector_type(4)));
typedef unsigned int u32;
typedef u32 u32x4 __attribute__((ext_vector_type(4)));
typedef u32 u32x2 __attribute__((ext_vector_type(2)));
typedef __fp16 h2_t __attribute__((ext_vector_type(2)));

__device__ inline short f2bf(float f){
  __hip_bfloat16 h = __float2bfloat16(f);
  return __builtin_bit_cast(short, h);
}
__device__ inline u32 pk2h(float a, float b){
#if __has_builtin(__builtin_amdgcn_cvt_pkrtz)
  h2_t r = __builtin_amdgcn_cvt_pkrtz(a, b);
  return __builtin_bit_cast(u32, r);
#else
  return (u32)__builtin_bit_cast(unsigned short, __float2half(a)) |
         ((u32)__builtin_bit_cast(unsigned short, __float2half(b)) << 16);
#endif
}
// fp8 e4m3 pack (2 floats -> low 16 bits) / unpack (HI = immediate template arg)
__device__ inline u32 pk_fp8(float a, float b){
#if __has_builtin(__builtin_amdgcn_cvt_pk_fp8_f32)
  return (u32)__builtin_amdgcn_cvt_pk_fp8_f32(a, b, 0, false);
#else
  __hip_fp8_e4m3 fa(a), fb(b);
  return (u32)fa.__x | ((u32)fb.__x << 8);
#endif
}
template<bool HI>
__device__ inline f2_t upk_fp8(u32 w){
#if __has_builtin(__builtin_amdgcn_cvt_pk_f32_fp8)
  return __builtin_amdgcn_cvt_pk_f32_fp8(w, HI);
#else
  const u32 hh = HI ? (w >> 16) : (w & 0xFFFFu);
  __hip_fp8_e4m3 a, b;
  a.__x = (unsigned char)(hh & 0xFF);
  b.__x = (unsigned char)(hh >> 8);
  return (f2_t){(float)a, (float)b};
#endif
}
// load 8 f32 weights and pack to bf16x8
__device__ inline s16x8 ldw8(const float* __restrict__ src){
  const f4_t v0 = *(const f4_t*)src;
  const f4_t v1 = *(const f4_t*)(src + 4);
  s16x8 o = { f2bf(v0[0]), f2bf(v0[1]), f2bf(v0[2]), f2bf(v0[3]),
              f2bf(v1[0]), f2bf(v1[1]), f2bf(v1[2]), f2bf(v1[3]) };
  return o;
}

// =============== K1: fused projection GEMM, 512-thread blocks (R18) =============
// bid < 256:  value-proj tile (BM=128, 8 waves) -> fp8 vfp8 (Cs-transposed)
// bid >= 256: offset/logit tile (BM=64, 8 waves) -> offw/logit f32
__global__ __launch_bounds__(512, 2) void k_proj(const float* __restrict__ value,
    const float* __restrict__ query, const float* __restrict__ Wval,
    const float* __restrict__ Woff, const float* __restrict__ Wattn,
    const float* __restrict__ bval, const float* __restrict__ boff,
    const float* __restrict__ battn, char* __restrict__ vfp8,
    float* __restrict__ offw, float* __restrict__ logit){
  __shared__ short As[128 * 256];               // 64KB
  __shared__ short Bs[64 * 256];                // 32KB
  __shared__ u32 Cs[2048];                      // 8KB fp8 transpose (val path)
  const int tid = threadIdx.x;
  const int lane = tid & 63, wv = tid >> 6;     // wv 0..7
  const int r16 = lane & 15, kh = lane >> 4;
  const int swsel = (r16 & 7) << 4;
  const int bid = blockIdx.x;

  if (bid < 256){
    // ---------------- value-projection path (BM=128) ----------------
    const int mbase = bid * 128;
    #pragma unroll
    for (int i = 0; i < 16; ++i){
      const int lin = i * 512 + tid;            // 128 rows x 64 chunks
      const int r = lin >> 6, ck = lin & 63;
      const f4_t v = *(const f4_t*)(value + (size_t)(mbase + r) * DK + ck * 4);
      s16x4 o = { f2bf(v[0]), f2bf(v[1]), f2bf(v[2]), f2bf(v[3]) };
      *(s16x4*)((char*)As + r * 512 + ((ck * 8) ^ ((r & 7) << 4))) = o;
    }
    s16x8 breg[4];
    #pragma unroll
    for (int i = 0; i < 4; ++i){
      const int lin = i * 512 + tid;            // 64 rows x 32 chunks
      const int n = lin >> 5, ck = lin & 31;
      breg[i] = ldw8(Wval + (size_t)n * DK + ck * 8);
    }
    __syncthreads();
    for (int cg = 0; cg < 4; ++cg){
      #pragma unroll
      for (int i = 0; i < 4; ++i){
        const int lin = i * 512 + tid;
        const int n = lin >> 5, ck = lin & 31;
        *(s16x8*)((char*)Bs + n * 512 + ((ck * 16) ^ ((n & 7) << 4))) = breg[i];
      }
      __syncthreads();
      if (cg < 3){
        #pragma unroll
        for (int i = 0; i < 4; ++i){
          const int lin = i * 512 + tid;
          const int n = lin >> 5, ck = lin & 31;
          breg[i] = ldw8(Wval + (size_t)((cg + 1) * 64 + n) * DK + ck * 8);
        }
      }
      f4_t acc[4];
      #pragma unroll
      for (int i = 0; i < 4; ++i) acc[i] = (f4_t){0.f, 0.f, 0.f, 0.f};
      #pragma unroll
      for (int kk = 0; kk < 8; ++kk){
        const int kb = kh * 16 + kk * 64;
        const s16x8 a = *(const s16x8*)((char*)As + (wv * 16 + r16) * 512 + (kb ^ swsel));
        #pragma unroll
        for (int nt = 0; nt < 4; ++nt){
          const s16x8 b = *(const s16x8*)((char*)Bs + (nt * 16 + r16) * 512 + (kb ^ swsel));
          acc[nt] = __builtin_amdgcn_mfma_f32_16x16x32_bf16(a, b, acc[nt], 0, 0, 0);
        }
      }
      // epilogue: f32 -> fp8, Cs[128 rows][64 col-bytes], coalesced 16B stores
      #pragma unroll
      for (int nt = 0; nt < 4; ++nt){
        const int n = cg * 64 + nt * 16 + r16;
        const float bv = bval[n];
        #pragma unroll
        for (int rix = 0; rix < 4; ++rix){
          const float vv = acc[nt][rix] + bv;
          ((char*)Cs)[(wv * 16 + kh * 4 + rix) * 64 + nt * 16 + r16] =
              (char)(pk_fp8(vv, 0.f) & 0xFFu);
        }
      }
      __syncthreads();                          // Cs ready; also fences Bs reads
      {
        const u32x4 cw = *((const u32x4*)((const char*)Cs + tid * 16));
        const int row = tid >> 2, q4 = tid & 3;
        const int h2 = cg * 2 + (q4 >> 1);
        const int m = mbase + row;
        const int r = m >> 14, pix = m & (QN - 1);
        *(u32x4*)(vfp8 + ((size_t)((r * 8 + h2) * QN + pix)) * 32 + (q4 & 1) * 16) = cw;
      }
    }
  } else {
    // ---------------- offset/logit path (BM=64) ----------------
    const int mg = wv >> 1, ch = wv & 1;        // 4 m-groups x 2 col-halves
    const int mbase = (bid - 256) * 64;
    #pragma unroll
    for (int i = 0; i < 8; ++i){
      const int lin = i * 512 + tid;            // 64 rows x 64 chunks
      const int r = lin >> 6, ck = lin & 63;
      const f4_t v = *(const f4_t*)(query + (size_t)(mbase + r) * DK + ck * 4);
      s16x4 o = { f2bf(v[0]), f2bf(v[1]), f2bf(v[2]), f2bf(v[3]) };
      *(s16x4*)((char*)As + r * 512 + ((ck * 8) ^ ((r & 7) << 4))) = o;
    }
    s16x8 breg[4];
    #pragma unroll
    for (int i = 0; i < 4; ++i){
      const int lin = i * 512 + tid;
      const int n = lin >> 5, ck = lin & 31;
      breg[i] = ldw8(Woff + (size_t)n * DK + ck * 8);
    }
    __syncthreads();
    for (int cg = 0; cg < 3; ++cg){
      #pragma unroll
      for (int i = 0; i < 4; ++i){
        const int lin = i * 512 + tid;
        const int n = lin >> 5, ck = lin & 31;
        *(s16x8*)((char*)Bs + n * 512 + ((ck * 16) ^ ((n & 7) << 4))) = breg[i];
      }
      __syncthreads();
      if (cg < 2){
        #pragma unroll
        for (int i = 0; i < 4; ++i){
          const int lin = i * 512 + tid;
          const int n = lin >> 5, ck = lin & 31;
          const int rrow = (cg + 1) * 64 + n;     // [64,192)
          const float* src = (rrow < 128) ? (Woff  + (size_t)rrow * DK)
                                          : (Wattn + (size_t)(rrow - 128) * DK);
          breg[i] = ldw8(src + ck * 8);
        }
      }
      f4_t acc[2];
      acc[0] = (f4_t){0.f,0.f,0.f,0.f}; acc[1] = (f4_t){0.f,0.f,0.f,0.f};
      #pragma unroll
      for (int kk = 0; kk < 8; ++kk){
        const int kb = kh * 16 + kk * 64;
        const s16x8 a = *(const s16x8*)((char*)As + (mg * 16 + r16) * 512 + (kb ^ swsel));
        #pragma unroll
        for (int nt = 0; nt < 2; ++nt){
          const s16x8 b = *(const s16x8*)((char*)Bs + (ch * 32 + nt * 16 + r16) * 512 + (kb ^ swsel));
          acc[nt] = __builtin_amdgcn_mfma_f32_16x16x32_bf16(a, b, acc[nt], 0, 0, 0);
        }
      }
      #pragma unroll
      for (int nt = 0; nt < 2; ++nt){
        const int n = cg * 64 + ch * 32 + nt * 16 + r16;
        #pragma unroll
        for (int rix = 0; rix < 4; ++rix){
          const int m = mbase + mg * 16 + kh * 4 + rix;
          const float v = acc[nt][rix];
          if (n < 128) offw[(size_t)m * 128 + n] = v + boff[n];
          else         logit[(size_t)m * 64 + (n - 128)] = v + battn[n - 128];
        }
      }
      __syncthreads();
    }
  }
}

// =============== K4: output projection, 512-thread BM=64 (R18-style widening) ===
__global__ __launch_bounds__(512, 2) void k_gemm_out(const short* __restrict__ Ab,
    const float* __restrict__ Wout, const float* __restrict__ bout,
    const float* __restrict__ query, float* __restrict__ out){
  __shared__ short As[64 * 256];                // 32KB (bf16 A, direct stage)
  __shared__ short Bs[64 * 256];                // 32KB
  const int tid = threadIdx.x;
  const int lane = tid & 63, wv = tid >> 6;     // wv 0..7
  const int r16 = lane & 15, kh = lane >> 4;
  const int mg = wv >> 1, ch = wv & 1;          // 4 m-groups x 2 col-halves
  const int swsel = (r16 & 7) << 4;
  const int mbase = blockIdx.x * 64;

  #pragma unroll
  for (int i = 0; i < 4; ++i){
    const int lin = i * 512 + tid;              // 64 rows x 32 chunks (16B)
    const int r = lin >> 5, ck = lin & 31;
    const s16x8 v = *(const s16x8*)(Ab + (size_t)(mbase + r) * DK + ck * 8);
    *(s16x8*)((char*)As + r * 512 + ((ck * 16) ^ ((r & 7) << 4))) = v;
  }
  s16x8 breg[4];
  #pragma unroll
  for (int i = 0; i < 4; ++i){
    const int lin = i * 512 + tid;
    const int n = lin >> 5, ck = lin & 31;
    breg[i] = ldw8(Wout + (size_t)n * DK + ck * 8);
  }
  __syncthreads();

  for (int cg = 0; cg < 4; ++cg){
    #pragma unroll
    for (int i = 0; i < 4; ++i){
      const int lin = i * 512 + tid;
      const int n = lin >> 5, ck = lin & 31;
      *(s16x8*)((char*)Bs + n * 512 + ((ck * 16) ^ ((n & 7) << 4))) = breg[i];
    }
    __syncthreads();
    if (cg < 3){
      #pragma unroll
      for (int i = 0; i < 4; ++i){
        const int lin = i * 512 + tid;
        const int n = lin >> 5, ck = lin & 31;
        breg[i] = ldw8(Wout + (size_t)((cg + 1) * 64 + n) * DK + ck * 8);
      }
    }
    f4_t acc[2];
    acc[0] = (f4_t){0.f,0.f,0.f,0.f}; acc[1] = (f4_t){0.f,0.f,0.f,0.f};
    #pragma unroll
    for (int kk = 0; kk < 8; ++kk){
      const int kb = kh * 16 + kk * 64;
      const s16x8 a = *(const s16x8*)((char*)As + (mg * 16 + r16) * 512 + (kb ^ swsel));
      #pragma unroll
      for (int nt = 0; nt < 2; ++nt){
        const s16x8 b = *(const s16x8*)((char*)Bs + (ch * 32 + nt * 16 + r16) * 512 + (kb ^ swsel));
        acc[nt] = __builtin_amdgcn_mfma_f32_16x16x32_bf16(a, b, acc[nt], 0, 0, 0);
      }
    }
    #pragma unroll
    for (int nt = 0; nt < 2; ++nt){
      const int n = cg * 64 + ch * 32 + nt * 16 + r16;
      const float bo = bout[n];
      #pragma unroll
      for (int rix = 0; rix < 4; ++rix){
        const int m = mbase + mg * 16 + kh * 4 + rix;
        out[(size_t)m * DK + n] = acc[nt][rix] + bo + query[(size_t)m * DK + n];
      }
    }
    __syncthreads();
  }
}

// ---------------- K3: bilinear sampling (EXACT R13) -----------------------------
__device__ inline void mkw(float rx, float ry, float ox, float oy, float awp,
                           u32& word, u32& pk01, u32& pk23){
  const float x = fmaf(rx, 128.f, ox) - 0.5f;
  const float y = fmaf(ry, 128.f, oy) - 0.5f;
  const float xf = floorf(x), yf = floorf(y);
  const float wx = x - xf, wy = y - yf;
  const int ix = (int)xf, iy = (int)yf;
  float xw0 = 1.f - wx, xw1 = wx, yw0 = 1.f - wy, yw1 = wy;
  if (ix < 0 || ix > 127)   xw0 = 0.f;
  if (ix < -1 || ix > 126)  xw1 = 0.f;
  if (iy < 0 || iy > 127)   yw0 = 0.f;
  if (iy < -1 || iy > 126)  yw1 = 0.f;
  const int ix0 = min(max(ix, 0), 127), ix1 = min(max(ix + 1, 0), 127);
  const int iy0 = min(max(iy, 0), 127), iy1 = min(max(iy + 1, 0), 127);
  const float t0 = awp * yw0, t1 = awp * yw1;
  pk01 = pk2h(t0 * xw0, t0 * xw1);     // (row0: x0-w, x1-w) fp16
  pk23 = pk2h(t1 * xw0, t1 * xw1);     // (row1: x0-w, x1-w) fp16
  word = (u32)(iy0 * 128 + ix0) | ((u32)(ix1 - ix0) << 16) | ((u32)(iy1 - iy0) << 17);
}

__global__ __launch_bounds__(256) void k_sampler(const float* __restrict__ rp,
    const float* __restrict__ offw, const float* __restrict__ logit,
    const char* __restrict__ vfp8, short* __restrict__ O2b){
  const int tid = threadIdx.x;
  const int j3 = tid & 7;               // lane in group
  const int row2 = j3 >> 2;             // row (y0 / y1)
  const int px2 = (j3 >> 1) & 1;        // pixel side (x0 / x1)
  const int ck2 = j3 & 1;               // channel half: [16*ck2, 16*ck2+16)
  const int grp = tid >> 3;             // query in block: 0..31
  const int lane = tid & 63;
  const int glane8 = lane & ~7;
  const int h = blockIdx.x & 7;
  const int q = (blockIdx.x >> 3) * 32 + grp;
  const u32 laneof = (u32)ck2 * 16;     // byte offset of my channel half

  const float* lp = logit + (size_t)q * 64 + h * 8;
  const float l = lp[j3];
  float m = l;
  m = fmaxf(m, __shfl_xor(m, 1)); m = fmaxf(m, __shfl_xor(m, 2)); m = fmaxf(m, __shfl_xor(m, 4));
  const float e = __expf(l - m);
  float ssum = e;
  ssum += __shfl_xor(ssum, 1); ssum += __shfl_xor(ssum, 2); ssum += __shfl_xor(ssum, 4);
  const float awp = e * (0.5f / ssum);

  const float* offp = offw + (size_t)q * 128 + h * 16;
  const float ox = offp[2 * j3], oy = offp[2 * j3 + 1];
  const int za2 = (j3 & 3) * 2;
  const float rx0 = rp[(size_t)q * 8 + za2],        ry0 = rp[(size_t)q * 8 + za2 + 1];
  const float rx1 = rp[(size_t)(QN + q) * 8 + za2], ry1 = rp[(size_t)(QN + q) * 8 + za2 + 1];

  u32 wrdA, pkA01, pkA23, wrdB, pkB01, pkB23;
  mkw(rx0, ry0, ox, oy, awp, wrdA, pkA01, pkA23);   // r=0 sample (owner: lane j3 = p)
  mkw(rx1, ry1, ox, oy, awp, wrdB, pkB01, pkB23);   // r=1 sample

  const char* vb0 = vfp8 + (size_t)(h * QN) * 32;
  const char* vb1 = vfp8 + (size_t)((8 + h) * QN) * 32;

  float acc[16];
  #pragma unroll
  for (int i = 0; i < 16; ++i) acc[i] = 0.f;

#define LOADP(S, WRD, VB)                                                   \
  const u32 wd_##S = __shfl((WRD), glane8 | ((S) & 7));                     \
  const u32 ad_##S = (wd_##S & 0xFFFFu) * 32u + laneof                      \
                   + (px2 ? ((wd_##S >> 11) & 32u) : 0u)                    \
                   + (row2 ? ((wd_##S >> 17) & 1u) * 4096u : 0u);           \
  const u32x4 c_##S = *(const u32x4*)((VB) + ad_##S);

#define USEP(S, PK01, PK23) do{                                             \
    const int srcl_ = glane8 | ((S) & 7);                                   \
    const u32 w01_ = __shfl((PK01), srcl_);                                 \
    const u32 w23_ = __shfl((PK23), srcl_);                                 \
    const u32 wsel_ = row2 ? w23_ : w01_;                                   \
    const h2_t wh_ = __builtin_bit_cast(h2_t, wsel_);                       \
    const float w_ = px2 ? (float)wh_[1] : (float)wh_[0];                   \
    _Pragma("unroll")                                                       \
    for (int i_ = 0; i_ < 4; ++i_){                                         \
      const f2_t lo_ = upk_fp8<false>(c_##S[i_]);                           \
      const f2_t hi_ = upk_fp8<true >(c_##S[i_]);                           \
      acc[4*i_+0] = fmaf(w_, lo_[0], acc[4*i_+0]);                          \
      acc[4*i_+1] = fmaf(w_, lo_[1], acc[4*i_+1]);                          \
      acc[4*i_+2] = fmaf(w_, hi_[0], acc[4*i_+2]);                          \
      acc[4*i_+3] = fmaf(w_, hi_[1], acc[4*i_+3]);                          \
    }                                                                       \
  }while(0)

  LOADP(0,  wrdA, vb0) LOADP(1,  wrdA, vb0) LOADP(2,  wrdA, vb0)
  USEP(0,  pkA01, pkA23); LOADP(3,  wrdA, vb0)
  USEP(1,  pkA01, pkA23); LOADP(4,  wrdA, vb0)
  USEP(2,  pkA01, pkA23); LOADP(5,  wrdA, vb0)
  USEP(3,  pkA01, pkA23); LOADP(6,  wrdA, vb0)
  USEP(4,  pkA01, pkA23); LOADP(7,  wrdA, vb0)
  USEP(5,  pkA01, pkA23); LOADP(8,  wrdB, vb1)
  USEP(6,  pkA01, pkA23); LOADP(9,  wrdB, vb1)
  USEP(7,  pkA01, pkA23); LOADP(10, wrdB, vb1)
  USEP(8,  pkB01, pkB23); LOADP(11, wrdB, vb1)
  USEP(9,  pkB01, pkB23); LOADP(12, wrdB, vb1)
  USEP(10, pkB01, pkB23); LOADP(13, wrdB, vb1)
  USEP(11, pkB01, pkB23); LOADP(14, wrdB, vb1)
  USEP(12, pkB01, pkB23); LOADP(15, wrdB, vb1)
  USEP(13, pkB01, pkB23);
  USEP(14, pkB01, pkB23);
  USEP(15, pkB01, pkB23);
#undef LOADP
#undef USEP

  #pragma unroll
  for (int i = 0; i < 16; ++i) acc[i] += __shfl_xor(acc[i], 4);
  #pragma unroll
  for (int i = 0; i < 16; ++i) acc[i] += __shfl_xor(acc[i], 2);
  if (j3 < 2){
    short* op = O2b + (size_t)q * DK + h * 32 + j3 * 16;
    s16x8 o0 = { f2bf(acc[0]),  f2bf(acc[1]),  f2bf(acc[2]),  f2bf(acc[3]),
                 f2bf(acc[4]),  f2bf(acc[5]),  f2bf(acc[6]),  f2bf(acc[7]) };
    s16x8 o1 = { f2bf(acc[8]),  f2bf(acc[9]),  f2bf(acc[10]), f2bf(acc[11]),
                 f2bf(acc[12]), f2bf(acc[13]), f2bf(acc[14]), f2bf(acc[15]) };
    *(s16x8*)op       = o0;
    *(s16x8*)(op + 8) = o1;
  }
}

extern "C" void kernel_launch(void* const* d_in, const int* in_sizes, int n_in,
                              void* d_out, int out_size, void* d_ws, size_t ws_size,
                              hipStream_t stream) {
  const float* query = (const float*)d_in[0];
  const float* value = (const float*)d_in[1];
  const float* refpt = (const float*)d_in[2];
  // d_in[3] spatial_shapes: fixed [[128,128]], hardcoded
  const float* W_off  = (const float*)d_in[4];
  const float* b_off  = (const float*)d_in[5];
  const float* W_attn = (const float*)d_in[6];
  const float* b_attn = (const float*)d_in[7];
  const float* W_val  = (const float*)d_in[8];
  const float* b_val  = (const float*)d_in[9];
  const float* W_out  = (const float*)d_in[10];
  const float* b_out  = (const float*)d_in[11];
  float* out = (float*)d_out;

  char* ws = (char*)d_ws;
  char*  vfp8 = (char*)(ws);                     // 2*8*16384*32 fp8      (8388608 B)
  float* offw = (float*)(ws + 8388608);          // 16384*128 f32         (8388608 B)
  float* logit= (float*)(ws + 16777216);         // 16384*64 f32          (4194304 B)
  short* O2b  = (short*)(ws + 20971520);         // 16384*256 bf16        (8388608 B)

  k_proj    <<<dim3(512),  dim3(512), 0, stream>>>(value, query, W_val, W_off, W_attn,
                                                   b_val, b_off, b_attn, vfp8, offw, logit);
  k_sampler <<<dim3(4096), dim3(256), 0, stream>>>(refpt, offw, logit, vfp8, O2b);
  k_gemm_out<<<dim3(256),  dim3(512), 0, stream>>>(O2b, W_out, b_out, query, out);
}